// Round 15
// baseline (173.618 us; speedup 1.0000x reference)
//
#include <hip/hip_runtime.h>
#include <hip/hip_bf16.h>

#define DIMC 1024
#define HEADS 16
#define HD 64
#define BATCH 2
#define SEQ 2048

typedef __bf16 bf16;
typedef __bf16 bf16x4 __attribute__((ext_vector_type(4)));
typedef __bf16 bf16x8 __attribute__((ext_vector_type(8)));
typedef float f32x4 __attribute__((ext_vector_type(4)));

typedef const __attribute__((address_space(1))) void* gas_t;
typedef __attribute__((address_space(3))) void* las_t;

__device__ inline f32x4 mfma_bf16(bf16x8 a, bf16x8 b, f32x4 c) {
    return __builtin_amdgcn_mfma_f32_16x16x32_bf16(a, b, c, 0, 0, 0);
}

// store 8 bf16 to LDS as two b64 (row strides are 8B- but not 16B-aligned)
__device__ inline void st8(bf16* p, bf16x8 v) {
    *(bf16x4*)p       = *(bf16x4*)&v;
    *(bf16x4*)(p + 4) = *((bf16x4*)&v + 1);
}
// load one MFMA operand fragment: elements 0..3 at k, 4..7 at k+16
__device__ inline bf16x8 ld_frag(const bf16* p) {
    bf16x8 r;
    *(bf16x4*)&r       = *(const bf16x4*)p;
    *((bf16x4*)&r + 1) = *(const bf16x4*)(p + 16);
    return r;
}
// fragment read from a linear [*, 64] LDS tile staged with 16B-chunk XOR:
// LDS[r][chunk c] = G[r][chunk c ^ (r&7)]. Want G chunk c0 = kk*4 + (lg>>1)
// (+2 for the k+16 half), in-chunk byte ib = (lg&1)*8. Chunk index and
// in-chunk byte computed SEPARATELY (byte-XOR would alias bit 4).
__device__ inline bf16x8 ld_frag_c(const bf16* tile, int row, int kk, int lg) {
    const char* rp = (const char*)(tile + row * 64);
    const int p = row & 7;
    const int c0 = kk * 4 + (lg >> 1);
    const int ib = (lg & 1) * 8;
    bf16x8 r;
    *(bf16x4*)&r       = *(const bf16x4*)(rp + ((((c0) ^ p) << 4) | ib));
    *((bf16x4*)&r + 1) = *(const bf16x4*)(rp + ((((c0 + 2) ^ p) << 4) | ib));
    return r;
}

// XCD-aware bijective block swizzle (nwg % 8 == 0): chunk grid per XCD so
// consecutive tiles (sharing an A panel) land on the same XCD's L2.
__device__ inline void swz_tile(int nx, int& m0, int& n0) {
    int flat = blockIdx.y * nx + blockIdx.x;
    int cpx = (nx * gridDim.y) >> 3;
    int s = (flat & 7) * cpx + (flat >> 3);
    n0 = (s % nx) * 128;
    m0 = (s / nx) * 128;
}

// ---------------- prep: sanitize x + cast both weights, one launch --------
// flat float4 space: [0,1048576) x | [1048576,1835008) qkv_w | rest proj_w
__global__ __launch_bounds__(256) void k_prep_all(const float* __restrict__ x,
                                                  const float* __restrict__ qw,
                                                  const float* __restrict__ pw,
                                                  bf16* __restrict__ xb,
                                                  bf16* __restrict__ wqkv,
                                                  bf16* __restrict__ wproj) {
    int idx = blockIdx.x * 1024 + threadIdx.x;
#pragma unroll
    for (int j = 0; j < 4; ++j, idx += 256) {
        if (idx < 1048576) {
            float4 v = ((const float4*)x)[idx];
            float a[4] = {v.x, v.y, v.z, v.w};
            bf16x4 o;
#pragma unroll
            for (int q = 0; q < 4; ++q) {
                float f = a[q];
                f = __builtin_isfinite(f) ? fminf(fmaxf(f, -10000.f), 10000.f) : 0.f;
                o[q] = (bf16)f;
            }
            ((bf16x4*)xb)[idx] = o;
        } else if (idx < 1835008) {
            int i2 = idx - 1048576;
            float4 v = ((const float4*)qw)[i2];
            bf16x4 o = {(bf16)v.x, (bf16)v.y, (bf16)v.z, (bf16)v.w};
            ((bf16x4*)wqkv)[i2] = o;
        } else {
            int i2 = idx - 1835008;
            float4 v = ((const float4*)pw)[i2];
            bf16x4 o = {(bf16)v.x, (bf16)v.y, (bf16)v.z, (bf16)v.w};
            ((bf16x4*)wproj)[i2] = o;
        }
    }
}

// ---------------- generic GEMM (used for proj): C = A * Bt^T --------------
// m97 structure: 128x128 tile, BK=64, linear LDS + global_load_lds width=16,
// 16B-chunk XOR swizzle. 4 waves (2x2), each wave 64x64.
template <bool OUT_BF16, bool BIAS, bool SANITIZE>
__global__ __launch_bounds__(256) void k_gemm_bt(const bf16* __restrict__ A,
                                                 const bf16* __restrict__ Bt,
                                                 void* __restrict__ Cv,
                                                 const float* __restrict__ bias,
                                                 int N, int K) {
    __shared__ alignas(16) bf16 As[128 * 64];
    __shared__ alignas(16) bf16 Bs[128 * 64];
    const int t = threadIdx.x;
    int m0, n0;
    swz_tile(N >> 7, m0, n0);
    const int w = t >> 6, lane = t & 63;
    const int wm = (w >> 1) * 64, wn = (w & 1) * 64;
    const int lr = lane & 15, lg = lane >> 4;
    const int srow = lane >> 3;
    const int scol = ((lane & 7) ^ srow) * 8;   // pre-swizzled global chunk

    f32x4 acc[4][4];
#pragma unroll
    for (int i = 0; i < 4; ++i)
#pragma unroll
        for (int j = 0; j < 4; ++j) acc[i][j] = 0.0f;

    for (int k0 = 0; k0 < K; k0 += 64) {
#pragma unroll
        for (int i = 0; i < 4; ++i) {
            int rg = w * 32 + i * 8;
            __builtin_amdgcn_global_load_lds(
                (gas_t)(A + (size_t)(m0 + rg + srow) * K + k0 + scol),
                (las_t)(As + rg * 64), 16, 0, 0);
            __builtin_amdgcn_global_load_lds(
                (gas_t)(Bt + (size_t)(n0 + rg + srow) * K + k0 + scol),
                (las_t)(Bs + rg * 64), 16, 0, 0);
        }
        __syncthreads();
#pragma unroll
        for (int kk = 0; kk < 2; ++kk) {
            bf16x8 af[4], bfr[4];
#pragma unroll
            for (int mi = 0; mi < 4; ++mi)
                af[mi] = ld_frag_c(As, wm + mi * 16 + lr, kk, lg);
#pragma unroll
            for (int ni = 0; ni < 4; ++ni)
                bfr[ni] = ld_frag_c(Bs, wn + ni * 16 + lr, kk, lg);
#pragma unroll
            for (int mi = 0; mi < 4; ++mi)
#pragma unroll
                for (int ni = 0; ni < 4; ++ni)
                    acc[mi][ni] = mfma_bf16(af[mi], bfr[ni], acc[mi][ni]);
        }
        __syncthreads();
    }
#pragma unroll
    for (int mi = 0; mi < 4; ++mi) {
#pragma unroll
        for (int ni = 0; ni < 4; ++ni) {
            int col = n0 + wn + ni * 16 + lr;
            float bval = BIAS ? bias[col] : 0.f;
#pragma unroll
            for (int r = 0; r < 4; ++r) {
                int row = m0 + wm + mi * 16 + lg * 4 + r;
                float v = acc[mi][ni][r];
                if (SANITIZE) v = __builtin_isfinite(v) ? v : 0.f;
                v += bval;
                if (OUT_BF16)
                    ((bf16*)Cv)[(size_t)row * N + col] = (bf16)v;
                else
                    ((float*)Cv)[(size_t)row * N + col] = v;
            }
        }
    }
}

// ---------------- qkv GEMM with fused rmsnorm+rope+v-transpose ------------
// Q/K blocks compute C^T = mfma(W,X) (swapped operands): lane then holds
// d = mi*16+lg*4+r IN-REGISTER for a single l = ni*16+lr -> RMSNorm is an
// in-lane 16-sum + 2 shfls, RoPE pairs are (r,r+1) in-lane, scales/pe load
// as float4, stores are bf16x4. V blocks keep normal orientation (their
// transposed store needs l-consecutive regs). sel is block-uniform.
__global__ __launch_bounds__(256) void k_gemm_qkv(const bf16* __restrict__ A,
                                                  const bf16* __restrict__ Bt,
                                                  const float* __restrict__ pe,
                                                  const float* __restrict__ q_scale,
                                                  const float* __restrict__ k_scale,
                                                  bf16* __restrict__ qb,
                                                  bf16* __restrict__ kb,
                                                  bf16* __restrict__ vt) {
    __shared__ alignas(16) bf16 As[128 * 64];
    __shared__ alignas(16) bf16 Bs[128 * 64];
    const int K = DIMC, t = threadIdx.x;
    int m0, n0;
    swz_tile(24, m0, n0);
    const int w = t >> 6, lane = t & 63;
    const int wm = (w >> 1) * 64, wn = (w & 1) * 64;
    const int lr = lane & 15, lg = lane >> 4;
    const int srow = lane >> 3;
    const int scol = ((lane & 7) ^ srow) * 8;
    const bool isV = (n0 >> 10) == 2;   // block-uniform

    f32x4 acc[4][4];
#pragma unroll
    for (int i = 0; i < 4; ++i)
#pragma unroll
        for (int j = 0; j < 4; ++j) acc[i][j] = 0.0f;

    for (int k0 = 0; k0 < K; k0 += 64) {
#pragma unroll
        for (int i = 0; i < 4; ++i) {
            int rg = w * 32 + i * 8;
            __builtin_amdgcn_global_load_lds(
                (gas_t)(A + (size_t)(m0 + rg + srow) * K + k0 + scol),
                (las_t)(As + rg * 64), 16, 0, 0);
            __builtin_amdgcn_global_load_lds(
                (gas_t)(Bt + (size_t)(n0 + rg + srow) * K + k0 + scol),
                (las_t)(Bs + rg * 64), 16, 0, 0);
        }
        __syncthreads();
#pragma unroll
        for (int kk = 0; kk < 2; ++kk) {
            bf16x8 xf[4], wf[4];
#pragma unroll
            for (int i = 0; i < 4; ++i)
                xf[i] = ld_frag_c(As, wm + i * 16 + lr, kk, lg);
#pragma unroll
            for (int i = 0; i < 4; ++i)
                wf[i] = ld_frag_c(Bs, wn + i * 16 + lr, kk, lg);
            if (isV) {
#pragma unroll
                for (int mi = 0; mi < 4; ++mi)
#pragma unroll
                    for (int ni = 0; ni < 4; ++ni)
                        acc[mi][ni] = mfma_bf16(xf[mi], wf[ni], acc[mi][ni]);
            } else {
#pragma unroll
                for (int mi = 0; mi < 4; ++mi)
#pragma unroll
                    for (int ni = 0; ni < 4; ++ni)
                        acc[mi][ni] = mfma_bf16(wf[mi], xf[ni], acc[mi][ni]);
            }
        }
        __syncthreads();
    }

    // ---- fused epilogue ----
    const int g = (n0 + wn) >> 6;          // head-slot 0..47
    const int sel = g >> 4;                // 0=q, 1=k, 2=v
    const int hh = g & 15;
    const int row0 = m0 + wm;              // global row base (l) of wave tile
    const int bb = row0 >> 11;
    const int l0 = row0 & (SEQ - 1);
    const size_t bhh = (size_t)(bb * HEADS + hh);

    // nan_to_num (reference sanitizes qkv before norm/rope) — positionless
#pragma unroll
    for (int mi = 0; mi < 4; ++mi)
#pragma unroll
        for (int ni = 0; ni < 4; ++ni)
#pragma unroll
            for (int r = 0; r < 4; ++r) {
                float v = acc[mi][ni][r];
                acc[mi][ni][r] = __builtin_isfinite(v) ? v : 0.f;
            }

    if (sel == 2) {
        // normal layout: d = ni*16+lr, l = mi*16+lg*4+r (4 consecutive l)
        // V: write transposed [B,H,D,L]
#pragma unroll
        for (int mi = 0; mi < 4; ++mi)
#pragma unroll
            for (int ni = 0; ni < 4; ++ni) {
                bf16x4 ov;
#pragma unroll
                for (int r = 0; r < 4; ++r) ov[r] = (bf16)acc[mi][ni][r];
                *(bf16x4*)(vt + (bhh * HD + ni * 16 + lr) * SEQ +
                           l0 + mi * 16 + lg * 4) = ov;
            }
    } else {
        // swapped layout: d = mi*16+lg*4+r (in-lane), l = ni*16+lr
        const float* sc = sel ? k_scale : q_scale;
        bf16* dst = sel ? kb : qb;
        // fold D^-0.5 * log2(e) into q
        const float oscale = sel ? 1.0f : 0.125f * 1.44269504088896340736f;
        float4 sc4[4];
#pragma unroll
        for (int mi = 0; mi < 4; ++mi)
            sc4[mi] = *(const float4*)(sc + mi * 16 + lg * 4);
#pragma unroll
        for (int ni = 0; ni < 4; ++ni) {
            float ss = 0.f;
#pragma unroll
            for (int mi = 0; mi < 4; ++mi)
#pragma unroll
                for (int r = 0; r < 4; ++r)
                    ss += acc[mi][ni][r] * acc[mi][ni][r];
            ss += __shfl_xor(ss, 16, 64);
            ss += __shfl_xor(ss, 32, 64);
            float rms = rsqrtf(ss * (1.f / 64.f) + 1e-6f);
            int l = l0 + ni * 16 + lr;
            const float* peb = pe + (size_t)l * 128 + (lg * 2) * 4;
            bf16* db = dst + (bhh * SEQ + l) * HD + lg * 4;
#pragma unroll
            for (int mi = 0; mi < 4; ++mi) {
                float4 pvA = *(const float4*)(peb + mi * 32);
                float4 pvB = *(const float4*)(peb + mi * 32 + 4);
                float e0 = acc[mi][ni][0] * rms * sc4[mi].x;
                float e1 = acc[mi][ni][1] * rms * sc4[mi].y;
                float e2 = acc[mi][ni][2] * rms * sc4[mi].z;
                float e3 = acc[mi][ni][3] * rms * sc4[mi].w;
                bf16x4 ov;
                ov[0] = (bf16)((pvA.x * e0 + pvA.y * e1) * oscale);
                ov[1] = (bf16)((pvA.z * e0 + pvA.w * e1) * oscale);
                ov[2] = (bf16)((pvB.x * e2 + pvB.y * e3) * oscale);
                ov[3] = (bf16)((pvB.z * e2 + pvB.w * e3) * oscale);
                *(bf16x4*)(db + mi * 16) = ov;
            }
        }
    }
}

// ---------------- flash attention (swapped QK^T, register P, O^T PV) ------
// 1D grid of 512 blocks, XCD-swizzled so each XCD owns 4 heads (K/V
// L2-resident, FETCH ~12MB measured). 512 threads = 8 waves, wave w ->
// q rows w*16..+16 of a 128-row tile. KVBLK=128 (16 barriers, 36 MFMA/tile).
// S^T = mfma(K, Q): lane holds S[q=w*16+lr][key = nk*16+lg*4+r].
// NO-SHIFT softmax: O = sum(P V)/sum(P) invariant to uniform 2^k scale of P;
// RMSNorm bounds s <= ~11.6 -> P = exp2(s) directly (no max/shuffle/branch).
// l via ones-MFMA. Reg-staged double-buffered K/V, T14 early issue.
// V stored as TWO [64][68] half-buffers (measured-conflict-free geometry).
__global__ __launch_bounds__(512) void k_attn(const bf16* __restrict__ Q,
                                              const bf16* __restrict__ Kb,
                                              const bf16* __restrict__ Vt,
                                              bf16* __restrict__ O) {
    __shared__ bf16 Ks[2][128][68];     // keys x d        34,816 B
    __shared__ bf16 Vs[2][2][64][68];   // half, d x keys  34,816 B
    // XCD swizzle: bid%8 = XCD; 64 consecutive work items per XCD
    // (= 4 full heads, qt fastest within a head).
    const int bid = blockIdx.x;
    const int s_id = (bid & 7) * 64 + (bid >> 3);
    const int qt = s_id & 15, bh = s_id >> 4;
    const int b = bh >> 4, h = bh & 15;
    const int t = threadIdx.x, w = t >> 6, lane = t & 63;
    const int lr = lane & 15, lg = lane >> 4;
    const size_t baseQK = (size_t)bh * SEQ * HD;
    const size_t baseVt = (size_t)bh * HD * SEQ;

    // Q fragments straight from global (lane-private; 4 x 8B loads)
    const bf16* qp = Q + baseQK + (size_t)(qt * 128 + w * 16 + lr) * HD;
    bf16x8 qf0 = ld_frag(qp + lg * 4);
    bf16x8 qf1 = ld_frag(qp + 32 + lg * 4);

    // staging: K rows t>>3 and 64+(t>>3), col (t&7)*8; V halves row t>>3.
    const int sr = t >> 3, sc8 = (t & 7) * 8;
    const bf16* kg0 = Kb + baseQK + (size_t)sr * HD + sc8;
    const bf16* vg0 = Vt + baseVt + (size_t)sr * SEQ + sc8;
    // stage K/V tile 0
    {
        bf16x8 k0 = *(const bf16x8*)(kg0);
        bf16x8 k1 = *(const bf16x8*)(kg0 + (size_t)64 * HD);
        bf16x8 v0 = *(const bf16x8*)(vg0);
        bf16x8 v1 = *(const bf16x8*)(vg0 + 64);
        st8(&Ks[0][sr][sc8], k0);
        st8(&Ks[0][64 + sr][sc8], k1);
        st8(&Vs[0][0][sr][sc8], v0);
        st8(&Vs[0][1][sr][sc8], v1);
    }
    __syncthreads();

    bf16x8 ones;
#pragma unroll
    for (int j = 0; j < 8; ++j) ones[j] = (bf16)1.0f;

    f32x4 oacc[4];
#pragma unroll
    for (int i = 0; i < 4; ++i) oacc[i] = 0.0f;
    f32x4 lacc = 0.0f;

    int cur = 0;
    for (int kt = 0; kt < SEQ / 128; ++kt) {
        // issue next tile's global loads early (latency hidden under compute)
        bf16x8 k0r, k1r, v0r, v1r;
        const bool pf = (kt + 1) < SEQ / 128;
        if (pf) {
            const bf16* kg = kg0 + (size_t)(kt + 1) * 128 * HD;
            const bf16* vg = vg0 + (kt + 1) * 128;
            k0r = *(const bf16x8*)(kg);
            k1r = *(const bf16x8*)(kg + (size_t)64 * HD);
            v0r = *(const bf16x8*)(vg);
            v1r = *(const bf16x8*)(vg + 64);
        }
        // QK^T on current tile: 8 key-blocks x 2 d-halves
        __builtin_amdgcn_s_setprio(1);
        f32x4 s[8];
#pragma unroll
        for (int nk = 0; nk < 8; ++nk) {
            f32x4 a = 0.0f;
            a = mfma_bf16(ld_frag(&Ks[cur][nk * 16 + lr][lg * 4]), qf0, a);
            a = mfma_bf16(ld_frag(&Ks[cur][nk * 16 + lr][32 + lg * 4]), qf1, a);
            s[nk] = a;
        }
        __builtin_amdgcn_s_setprio(0);
        // P = exp2(s), packed straight into A-frag layout; all lanes
        // independent -> exp2s pipeline freely, zero cross-lane traffic.
        bf16x8 pa[4];
#pragma unroll
        for (int c = 0; c < 4; ++c)
#pragma unroll
            for (int j = 0; j < 4; ++j) {
                pa[c][j]     = (bf16)exp2f(s[2 * c][j]);
                pa[c][4 + j] = (bf16)exp2f(s[2 * c + 1][j]);
            }
        __builtin_amdgcn_s_setprio(1);
        // l row-sum via ones-MFMA (lands in col q = lane&15, all regs equal)
#pragma unroll
        for (int c = 0; c < 4; ++c) lacc = mfma_bf16(ones, pa[c], lacc);
        // PV over 4 key-chunks of 32: half = c>>1, local col = (c&1)*32
#pragma unroll
        for (int nd = 0; nd < 4; ++nd)
#pragma unroll
            for (int c = 0; c < 4; ++c)
                oacc[nd] = mfma_bf16(
                    ld_frag(&Vs[cur][c >> 1][nd * 16 + lr][(c & 1) * 32 + lg * 4]),
                    pa[c], oacc[nd]);
        __builtin_amdgcn_s_setprio(0);
        // write prefetched tile into the other buffer (readers of it synced
        // at the end of iteration kt-1)
        if (pf) {
            st8(&Ks[cur ^ 1][sr][sc8], k0r);
            st8(&Ks[cur ^ 1][64 + sr][sc8], k1r);
            st8(&Vs[cur ^ 1][0][sr][sc8], v0r);
            st8(&Vs[cur ^ 1][1][sr][sc8], v1r);
        }
        __syncthreads();
        cur ^= 1;
    }
    // epilogue: O^T[d][q] regs -> O[b, q, h*64+d], d = nd*16+lg*4+r (4 consecutive)
    {
        float inv = 1.f / lacc[0];
        int q = qt * 128 + w * 16 + lr;
#pragma unroll
        for (int nd = 0; nd < 4; ++nd) {
            bf16x4 ov;
#pragma unroll
            for (int r2 = 0; r2 < 4; ++r2) {
                float v = oacc[nd][r2] * inv;
                v = fminf(fmaxf(v, -10000.f), 10000.f);
                ov[r2] = (bf16)v;
            }
            *(bf16x4*)(O + ((size_t)(b * SEQ + q)) * DIMC + h * HD + nd * 16 + lg * 4) = ov;
        }
    }
}

extern "C" void kernel_launch(void* const* d_in, const int* in_sizes, int n_in,
                              void* d_out, int out_size, void* d_ws, size_t ws_size,
                              hipStream_t stream) {
    const float* x = (const float*)d_in[0];
    const float* pe = (const float*)d_in[1];
    const float* qkv_w = (const float*)d_in[2];
    const float* q_scale = (const float*)d_in[3];
    const float* k_scale = (const float*)d_in[4];
    const float* proj_w = (const float*)d_in[5];
    const float* proj_b = (const float*)d_in[6];
    float* out = (float*)d_out;
    char* ws = (char*)d_ws;

    // workspace layout (48 MB used)
    bf16* xb = (bf16*)(ws);                              // 8 MB  [4096][1024]
    bf16* wqkv = (bf16*)(ws + (8u << 20));               // 6 MB  [3072][1024]
    bf16* wproj = (bf16*)(ws + (14u << 20));             // 2 MB  [1024][1024]
    bf16* ao = (bf16*)(ws + (16u << 20));                // 8 MB  attn out bf16
    bf16* qb = (bf16*)(ws + (24u << 20));                // 8 MB  [B,H,L,D]
    bf16* kb = (bf16*)(ws + (32u << 20));                // 8 MB  [B,H,L,D]
    bf16* vt = (bf16*)(ws + (40u << 20));                // 8 MB  [B,H,D,L]

    k_prep_all<<<2048, 256, 0, stream>>>(x, qkv_w, proj_w, xb, wqkv, wproj);
    // qkv GEMM + fused nan_to_num/rmsnorm/rope/v-transpose
    k_gemm_qkv<<<dim3(24, 32), 256, 0, stream>>>(xb, wqkv, pe, q_scale, k_scale,
                                                 qb, kb, vt);
    k_attn<<<512, 512, 0, stream>>>(qb, kb, vt, ao);
    // out = attn_out @ proj_w^T + proj_b (clip already applied in k_attn)
    k_gemm_bt<false, true, false>
        <<<dim3(8, 32), 256, 0, stream>>>(ao, wproj, (void*)out, proj_b, 1024, 1024);
}

// Round 16
// 156.102 us; speedup vs baseline: 1.1122x; 1.1122x over previous
//
#include <hip/hip_runtime.h>
#include <hip/hip_bf16.h>

#define DIMC 1024
#define HEADS 16
#define HD 64
#define BATCH 2
#define SEQ 2048

typedef __bf16 bf16;
typedef __bf16 bf16x4 __attribute__((ext_vector_type(4)));
typedef __bf16 bf16x8 __attribute__((ext_vector_type(8)));
typedef float f32x4 __attribute__((ext_vector_type(4)));

typedef const __attribute__((address_space(1))) void* gas_t;
typedef __attribute__((address_space(3))) void* las_t;

__device__ inline f32x4 mfma_bf16(bf16x8 a, bf16x8 b, f32x4 c) {
    return __builtin_amdgcn_mfma_f32_16x16x32_bf16(a, b, c, 0, 0, 0);
}

// store 8 bf16 to LDS as two b64 (row strides are 8B- but not 16B-aligned)
__device__ inline void st8(bf16* p, bf16x8 v) {
    *(bf16x4*)p       = *(bf16x4*)&v;
    *(bf16x4*)(p + 4) = *((bf16x4*)&v + 1);
}
// load one MFMA operand fragment: elements 0..3 at k, 4..7 at k+16
__device__ inline bf16x8 ld_frag(const bf16* p) {
    bf16x8 r;
    *(bf16x4*)&r       = *(const bf16x4*)p;
    *((bf16x4*)&r + 1) = *(const bf16x4*)(p + 16);
    return r;
}
// FRAG-PERMUTED layout: global rows are pre-permuted per 64-elem K-block so
// slot s = kk*4+lg (16B) holds elements [kk*32+lg*4 .. +4, kk*32+lg*4+16 ..+20]
// = exactly one MFMA fragment -> single b128 read. LDS stores slot s of row r
// at chunk s ^ (r&7) (matches staging scol); banks: 2 lanes/bank = free.
__device__ inline bf16x8 ld_frag8(const bf16* tile, int row, int s) {
    return *(const bf16x8*)(tile + row * 64 + (((s) ^ (row & 7)) << 3));
}
// permute a float4-group index within its 64-elem (16-group) block: dst group
// G=(s<<1)|h  <-  src group (s>>2)*8 + h*4 + (s&3)
__device__ inline int perm_src4(int d4) {
    int G = d4 & 15;
    int s = G >> 1, h = G & 1;
    int srcG = ((s >> 2) << 3) + (h << 2) + (s & 3);
    return (d4 & ~15) | srcG;
}

// XCD-aware bijective block swizzle (nwg % 8 == 0): chunk grid per XCD so
// consecutive tiles (sharing an A panel) land on the same XCD's L2.
__device__ inline void swz_tile(int nx, int& m0, int& n0) {
    int flat = blockIdx.y * nx + blockIdx.x;
    int cpx = (nx * gridDim.y) >> 3;
    int s = (flat & 7) * cpx + (flat >> 3);
    n0 = (s % nx) * 128;
    m0 = (s / nx) * 128;
}

// ---------------- prep: sanitize x + cast both weights, one launch --------
// Writes xb/wqkv/wproj in FRAG-PERMUTED row layout (see ld_frag8).
// flat float4 space: [0,1048576) x | [1048576,1835008) qkv_w | rest proj_w
__global__ __launch_bounds__(256) void k_prep_all(const float* __restrict__ x,
                                                  const float* __restrict__ qw,
                                                  const float* __restrict__ pw,
                                                  bf16* __restrict__ xb,
                                                  bf16* __restrict__ wqkv,
                                                  bf16* __restrict__ wproj) {
    int idx = blockIdx.x * 1024 + threadIdx.x;
#pragma unroll
    for (int j = 0; j < 4; ++j, idx += 256) {
        if (idx < 1048576) {
            float4 v = ((const float4*)x)[perm_src4(idx)];
            float a[4] = {v.x, v.y, v.z, v.w};
            bf16x4 o;
#pragma unroll
            for (int q = 0; q < 4; ++q) {
                float f = a[q];
                f = __builtin_isfinite(f) ? fminf(fmaxf(f, -10000.f), 10000.f) : 0.f;
                o[q] = (bf16)f;
            }
            ((bf16x4*)xb)[idx] = o;
        } else if (idx < 1835008) {
            int i2 = idx - 1048576;
            float4 v = ((const float4*)qw)[perm_src4(i2)];
            bf16x4 o = {(bf16)v.x, (bf16)v.y, (bf16)v.z, (bf16)v.w};
            ((bf16x4*)wqkv)[i2] = o;
        } else {
            int i2 = idx - 1835008;
            float4 v = ((const float4*)pw)[perm_src4(i2)];
            bf16x4 o = {(bf16)v.x, (bf16)v.y, (bf16)v.z, (bf16)v.w};
            ((bf16x4*)wproj)[i2] = o;
        }
    }
}

// ---------------- generic GEMM (used for proj): C = A * Bt^T --------------
// m97 structure: 128x128 tile, BK=64, linear LDS + global_load_lds width=16,
// frag-permuted K layout -> single b128 frag reads. 4 waves, 64x64 each.
template <bool OUT_BF16, bool BIAS, bool SANITIZE>
__global__ __launch_bounds__(256) void k_gemm_bt(const bf16* __restrict__ A,
                                                 const bf16* __restrict__ Bt,
                                                 void* __restrict__ Cv,
                                                 const float* __restrict__ bias,
                                                 int N, int K) {
    __shared__ alignas(16) bf16 As[128 * 64];
    __shared__ alignas(16) bf16 Bs[128 * 64];
    const int t = threadIdx.x;
    int m0, n0;
    swz_tile(N >> 7, m0, n0);
    const int w = t >> 6, lane = t & 63;
    const int wm = (w >> 1) * 64, wn = (w & 1) * 64;
    const int lr = lane & 15, lg = lane >> 4;
    const int srow = lane >> 3;
    const int scol = ((lane & 7) ^ srow) * 8;   // pre-swizzled global chunk

    f32x4 acc[4][4];
#pragma unroll
    for (int i = 0; i < 4; ++i)
#pragma unroll
        for (int j = 0; j < 4; ++j) acc[i][j] = 0.0f;

    for (int k0 = 0; k0 < K; k0 += 64) {
#pragma unroll
        for (int i = 0; i < 4; ++i) {
            int rg = w * 32 + i * 8;
            __builtin_amdgcn_global_load_lds(
                (gas_t)(A + (size_t)(m0 + rg + srow) * K + k0 + scol),
                (las_t)(As + rg * 64), 16, 0, 0);
            __builtin_amdgcn_global_load_lds(
                (gas_t)(Bt + (size_t)(n0 + rg + srow) * K + k0 + scol),
                (las_t)(Bs + rg * 64), 16, 0, 0);
        }
        __syncthreads();
#pragma unroll
        for (int kk = 0; kk < 2; ++kk) {
            bf16x8 af[4], bfr[4];
#pragma unroll
            for (int mi = 0; mi < 4; ++mi)
                af[mi] = ld_frag8(As, wm + mi * 16 + lr, kk * 4 + lg);
#pragma unroll
            for (int ni = 0; ni < 4; ++ni)
                bfr[ni] = ld_frag8(Bs, wn + ni * 16 + lr, kk * 4 + lg);
#pragma unroll
            for (int mi = 0; mi < 4; ++mi)
#pragma unroll
                for (int ni = 0; ni < 4; ++ni)
                    acc[mi][ni] = mfma_bf16(af[mi], bfr[ni], acc[mi][ni]);
        }
        __syncthreads();
    }
#pragma unroll
    for (int mi = 0; mi < 4; ++mi) {
#pragma unroll
        for (int ni = 0; ni < 4; ++ni) {
            int col = n0 + wn + ni * 16 + lr;
            float bval = BIAS ? bias[col] : 0.f;
#pragma unroll
            for (int r = 0; r < 4; ++r) {
                int row = m0 + wm + mi * 16 + lg * 4 + r;
                float v = acc[mi][ni][r];
                if (SANITIZE) v = __builtin_isfinite(v) ? v : 0.f;
                v += bval;
                if (OUT_BF16)
                    ((bf16*)Cv)[(size_t)row * N + col] = (bf16)v;
                else
                    ((float*)Cv)[(size_t)row * N + col] = v;
            }
        }
    }
}

// ---------------- qkv GEMM, split by output kind (template) ---------------
// MODE 0 (q/k, grid 16x32): C^T = mfma(W,X); lane holds d = mi*16+lg*4+r
//   in-register for l = ni*16+lr -> in-lane RMSNorm (+2 shfl), in-lane RoPE,
//   float4 scale/pe loads, bf16x4 stores.
// MODE 1 (V, grid 8x32, n0+=2048): normal orientation; transposed store
//   needs l-consecutive regs.
template <int MODE>
__global__ __launch_bounds__(256) void k_gemm_qkv(const bf16* __restrict__ A,
                                                  const bf16* __restrict__ Bt,
                                                  const float* __restrict__ pe,
                                                  const float* __restrict__ q_scale,
                                                  const float* __restrict__ k_scale,
                                                  bf16* __restrict__ qb,
                                                  bf16* __restrict__ kb,
                                                  bf16* __restrict__ vt) {
    __shared__ alignas(16) bf16 As[128 * 64];
    __shared__ alignas(16) bf16 Bs[128 * 64];
    const int K = DIMC, t = threadIdx.x;
    int m0, n0;
    if (MODE == 0) {
        swz_tile(16, m0, n0);
    } else {
        swz_tile(8, m0, n0);
        n0 += 2048;
    }
    const int w = t >> 6, lane = t & 63;
    const int wm = (w >> 1) * 64, wn = (w & 1) * 64;
    const int lr = lane & 15, lg = lane >> 4;
    const int srow = lane >> 3;
    const int scol = ((lane & 7) ^ srow) * 8;

    f32x4 acc[4][4];
#pragma unroll
    for (int i = 0; i < 4; ++i)
#pragma unroll
        for (int j = 0; j < 4; ++j) acc[i][j] = 0.0f;

    for (int k0 = 0; k0 < K; k0 += 64) {
#pragma unroll
        for (int i = 0; i < 4; ++i) {
            int rg = w * 32 + i * 8;
            __builtin_amdgcn_global_load_lds(
                (gas_t)(A + (size_t)(m0 + rg + srow) * K + k0 + scol),
                (las_t)(As + rg * 64), 16, 0, 0);
            __builtin_amdgcn_global_load_lds(
                (gas_t)(Bt + (size_t)(n0 + rg + srow) * K + k0 + scol),
                (las_t)(Bs + rg * 64), 16, 0, 0);
        }
        __syncthreads();
#pragma unroll
        for (int kk = 0; kk < 2; ++kk) {
            bf16x8 xf[4], wf[4];
#pragma unroll
            for (int i = 0; i < 4; ++i)
                xf[i] = ld_frag8(As, wm + i * 16 + lr, kk * 4 + lg);
#pragma unroll
            for (int i = 0; i < 4; ++i)
                wf[i] = ld_frag8(Bs, wn + i * 16 + lr, kk * 4 + lg);
#pragma unroll
            for (int mi = 0; mi < 4; ++mi)
#pragma unroll
                for (int ni = 0; ni < 4; ++ni)
                    acc[mi][ni] = (MODE == 1)
                                      ? mfma_bf16(xf[mi], wf[ni], acc[mi][ni])
                                      : mfma_bf16(wf[mi], xf[ni], acc[mi][ni]);
        }
        __syncthreads();
    }

    // ---- fused epilogue ----
    const int g = (n0 + wn) >> 6;          // head-slot 0..47
    const int sel = g >> 4;                // 0=q, 1=k, 2=v
    const int hh = g & 15;
    const int row0 = m0 + wm;              // global row base (l) of wave tile
    const int bb = row0 >> 11;
    const int l0 = row0 & (SEQ - 1);
    const size_t bhh = (size_t)(bb * HEADS + hh);

    // nan_to_num (reference sanitizes qkv before norm/rope) — positionless
#pragma unroll
    for (int mi = 0; mi < 4; ++mi)
#pragma unroll
        for (int ni = 0; ni < 4; ++ni)
#pragma unroll
            for (int r = 0; r < 4; ++r) {
                float v = acc[mi][ni][r];
                acc[mi][ni][r] = __builtin_isfinite(v) ? v : 0.f;
            }

    if (MODE == 1) {
        // normal layout: d = ni*16+lr, l = mi*16+lg*4+r (4 consecutive l)
        // V: write transposed [B,H,D,L]
#pragma unroll
        for (int mi = 0; mi < 4; ++mi)
#pragma unroll
            for (int ni = 0; ni < 4; ++ni) {
                bf16x4 ov;
#pragma unroll
                for (int r = 0; r < 4; ++r) ov[r] = (bf16)acc[mi][ni][r];
                *(bf16x4*)(vt + (bhh * HD + ni * 16 + lr) * SEQ +
                           l0 + mi * 16 + lg * 4) = ov;
            }
    } else {
        // swapped layout: d = mi*16+lg*4+r (in-lane), l = ni*16+lr
        const float* sc = sel ? k_scale : q_scale;
        bf16* dst = sel ? kb : qb;
        // fold D^-0.5 * log2(e) into q
        const float oscale = sel ? 1.0f : 0.125f * 1.44269504088896340736f;
        float4 sc4[4];
#pragma unroll
        for (int mi = 0; mi < 4; ++mi)
            sc4[mi] = *(const float4*)(sc + mi * 16 + lg * 4);
#pragma unroll
        for (int ni = 0; ni < 4; ++ni) {
            float ss = 0.f;
#pragma unroll
            for (int mi = 0; mi < 4; ++mi)
#pragma unroll
                for (int r = 0; r < 4; ++r)
                    ss += acc[mi][ni][r] * acc[mi][ni][r];
            ss += __shfl_xor(ss, 16, 64);
            ss += __shfl_xor(ss, 32, 64);
            float rms = rsqrtf(ss * (1.f / 64.f) + 1e-6f);
            int l = l0 + ni * 16 + lr;
            const float* peb = pe + (size_t)l * 128 + (lg * 2) * 4;
            bf16* db = dst + (bhh * SEQ + l) * HD + lg * 4;
#pragma unroll
            for (int mi = 0; mi < 4; ++mi) {
                float4 pvA = *(const float4*)(peb + mi * 32);
                float4 pvB = *(const float4*)(peb + mi * 32 + 4);
                float e0 = acc[mi][ni][0] * rms * sc4[mi].x;
                float e1 = acc[mi][ni][1] * rms * sc4[mi].y;
                float e2 = acc[mi][ni][2] * rms * sc4[mi].z;
                float e3 = acc[mi][ni][3] * rms * sc4[mi].w;
                bf16x4 ov;
                ov[0] = (bf16)((pvA.x * e0 + pvA.y * e1) * oscale);
                ov[1] = (bf16)((pvA.z * e0 + pvA.w * e1) * oscale);
                ov[2] = (bf16)((pvB.x * e2 + pvB.y * e3) * oscale);
                ov[3] = (bf16)((pvB.z * e2 + pvB.w * e3) * oscale);
                *(bf16x4*)(db + mi * 16) = ov;
            }
        }
    }
}

// ---------------- flash attention (swapped QK^T, register P, O^T PV) ------
// 1D grid of 512 blocks, XCD-swizzled so each XCD owns 4 heads (K/V
// L2-resident, FETCH ~12MB measured). 512 threads = 8 waves, wave w ->
// q rows w*16..+16 of a 128-row tile. KVBLK=128 (16 barriers, 36 MFMA/tile).
// NO-SHIFT softmax (P = exp2(s) directly); l via ones-MFMA.
// Reg-staged double-buffered K/V; V as two [64][68] half-buffers (0-conflict).
// O written in the FRAG-PERMUTED column layout that k_gemm_bt expects.
__global__ __launch_bounds__(512) void k_attn(const bf16* __restrict__ Q,
                                              const bf16* __restrict__ Kb,
                                              const bf16* __restrict__ Vt,
                                              bf16* __restrict__ O) {
    __shared__ bf16 Ks[2][128][68];     // keys x d        34,816 B
    __shared__ bf16 Vs[2][2][64][68];   // half, d x keys  34,816 B
    const int bid = blockIdx.x;
    const int s_id = (bid & 7) * 64 + (bid >> 3);
    const int qt = s_id & 15, bh = s_id >> 4;
    const int b = bh >> 4, h = bh & 15;
    const int t = threadIdx.x, w = t >> 6, lane = t & 63;
    const int lr = lane & 15, lg = lane >> 4;
    const size_t baseQK = (size_t)bh * SEQ * HD;
    const size_t baseVt = (size_t)bh * HD * SEQ;

    // Q fragments straight from global (lane-private; 4 x 8B loads)
    const bf16* qp = Q + baseQK + (size_t)(qt * 128 + w * 16 + lr) * HD;
    bf16x8 qf0 = ld_frag(qp + lg * 4);
    bf16x8 qf1 = ld_frag(qp + 32 + lg * 4);

    // staging: K rows t>>3 and 64+(t>>3), col (t&7)*8; V halves row t>>3.
    const int sr = t >> 3, sc8 = (t & 7) * 8;
    const bf16* kg0 = Kb + baseQK + (size_t)sr * HD + sc8;
    const bf16* vg0 = Vt + baseVt + (size_t)sr * SEQ + sc8;
    // stage K/V tile 0
    {
        bf16x8 k0 = *(const bf16x8*)(kg0);
        bf16x8 k1 = *(const bf16x8*)(kg0 + (size_t)64 * HD);
        bf16x8 v0 = *(const bf16x8*)(vg0);
        bf16x8 v1 = *(const bf16x8*)(vg0 + 64);
        st8(&Ks[0][sr][sc8], k0);
        st8(&Ks[0][64 + sr][sc8], k1);
        st8(&Vs[0][0][sr][sc8], v0);
        st8(&Vs[0][1][sr][sc8], v1);
    }
    __syncthreads();

    bf16x8 ones;
#pragma unroll
    for (int j = 0; j < 8; ++j) ones[j] = (bf16)1.0f;

    f32x4 oacc[4];
#pragma unroll
    for (int i = 0; i < 4; ++i) oacc[i] = 0.0f;
    f32x4 lacc = 0.0f;

    int cur = 0;
    for (int kt = 0; kt < SEQ / 128; ++kt) {
        // issue next tile's global loads early (latency hidden under compute)
        bf16x8 k0r, k1r, v0r, v1r;
        const bool pf = (kt + 1) < SEQ / 128;
        if (pf) {
            const bf16* kg = kg0 + (size_t)(kt + 1) * 128 * HD;
            const bf16* vg = vg0 + (kt + 1) * 128;
            k0r = *(const bf16x8*)(kg);
            k1r = *(const bf16x8*)(kg + (size_t)64 * HD);
            v0r = *(const bf16x8*)(vg);
            v1r = *(const bf16x8*)(vg + 64);
        }
        // QK^T on current tile: 8 key-blocks x 2 d-halves
        __builtin_amdgcn_s_setprio(1);
        f32x4 s[8];
#pragma unroll
        for (int nk = 0; nk < 8; ++nk) {
            f32x4 a = 0.0f;
            a = mfma_bf16(ld_frag(&Ks[cur][nk * 16 + lr][lg * 4]), qf0, a);
            a = mfma_bf16(ld_frag(&Ks[cur][nk * 16 + lr][32 + lg * 4]), qf1, a);
            s[nk] = a;
        }
        __builtin_amdgcn_s_setprio(0);
        // P = exp2(s), packed straight into A-frag layout
        bf16x8 pa[4];
#pragma unroll
        for (int c = 0; c < 4; ++c)
#pragma unroll
            for (int j = 0; j < 4; ++j) {
                pa[c][j]     = (bf16)exp2f(s[2 * c][j]);
                pa[c][4 + j] = (bf16)exp2f(s[2 * c + 1][j]);
            }
        __builtin_amdgcn_s_setprio(1);
        // l row-sum via ones-MFMA (lands in col q = lane&15, all regs equal)
#pragma unroll
        for (int c = 0; c < 4; ++c) lacc = mfma_bf16(ones, pa[c], lacc);
        // PV over 4 key-chunks of 32: half = c>>1, local col = (c&1)*32
#pragma unroll
        for (int nd = 0; nd < 4; ++nd)
#pragma unroll
            for (int c = 0; c < 4; ++c)
                oacc[nd] = mfma_bf16(
                    ld_frag(&Vs[cur][c >> 1][nd * 16 + lr][(c & 1) * 32 + lg * 4]),
                    pa[c], oacc[nd]);
        __builtin_amdgcn_s_setprio(0);
        if (pf) {
            st8(&Ks[cur ^ 1][sr][sc8], k0r);
            st8(&Ks[cur ^ 1][64 + sr][sc8], k1r);
            st8(&Vs[cur ^ 1][0][sr][sc8], v0r);
            st8(&Vs[cur ^ 1][1][sr][sc8], v1r);
        }
        __syncthreads();
        cur ^= 1;
    }
    // epilogue: O^T[d][q] regs -> O[b, q, head-block col in frag-permuted
    // layout]: element d = nd*16+lg*4+r maps to slot (nd>>1)*4+lg, half nd&1.
    {
        float inv = 1.f / lacc[0];
        int q = qt * 128 + w * 16 + lr;
#pragma unroll
        for (int nd = 0; nd < 4; ++nd) {
            bf16x4 ov;
#pragma unroll
            for (int r2 = 0; r2 < 4; ++r2) {
                float v = oacc[nd][r2] * inv;
                v = fminf(fmaxf(v, -10000.f), 10000.f);
                ov[r2] = (bf16)v;
            }
            int colb = (((nd >> 1) * 4 + lg) << 3) + (nd & 1) * 4;
            *(bf16x4*)(O + ((size_t)(b * SEQ + q)) * DIMC + h * HD + colb) = ov;
        }
    }
}

extern "C" void kernel_launch(void* const* d_in, const int* in_sizes, int n_in,
                              void* d_out, int out_size, void* d_ws, size_t ws_size,
                              hipStream_t stream) {
    const float* x = (const float*)d_in[0];
    const float* pe = (const float*)d_in[1];
    const float* qkv_w = (const float*)d_in[2];
    const float* q_scale = (const float*)d_in[3];
    const float* k_scale = (const float*)d_in[4];
    const float* proj_w = (const float*)d_in[5];
    const float* proj_b = (const float*)d_in[6];
    float* out = (float*)d_out;
    char* ws = (char*)d_ws;

    // workspace layout (48 MB used)
    bf16* xb = (bf16*)(ws);                              // 8 MB  [4096][1024] (frag-permuted K)
    bf16* wqkv = (bf16*)(ws + (8u << 20));               // 6 MB  [3072][1024] (frag-permuted K)
    bf16* wproj = (bf16*)(ws + (14u << 20));             // 2 MB  [1024][1024] (frag-permuted K)
    bf16* ao = (bf16*)(ws + (16u << 20));                // 8 MB  attn out (frag-permuted cols)
    bf16* qb = (bf16*)(ws + (24u << 20));                // 8 MB  [B,H,L,D]
    bf16* kb = (bf16*)(ws + (32u << 20));                // 8 MB  [B,H,L,D]
    bf16* vt = (bf16*)(ws + (40u << 20));                // 8 MB  [B,H,D,L]

    k_prep_all<<<2048, 256, 0, stream>>>(x, qkv_w, proj_w, xb, wqkv, wproj);
    // qkv GEMM split: q/k (swapped epilogue) and V (transposed store)
    k_gemm_qkv<0><<<dim3(16, 32), 256, 0, stream>>>(xb, wqkv, pe, q_scale,
                                                    k_scale, qb, kb, vt);
    k_gemm_qkv<1><<<dim3(8, 32), 256, 0, stream>>>(xb, wqkv, pe, q_scale,
                                                   k_scale, qb, kb, vt);
    k_attn<<<512, 512, 0, stream>>>(qb, kb, vt, ao);
    // out = attn_out @ proj_w^T + proj_b (clip already applied in k_attn)
    k_gemm_bt<false, true, false>
        <<<dim3(8, 32), 256, 0, stream>>>(ao, wproj, (void*)out, proj_b, 1024, 1024);
}

// Round 17
// 137.140 us; speedup vs baseline: 1.2660x; 1.1383x over previous
//
#include <hip/hip_runtime.h>
#include <hip/hip_bf16.h>

#define DIMC 1024
#define HEADS 16
#define HD 64
#define BATCH 2
#define SEQ 2048

typedef __bf16 bf16;
typedef __bf16 bf16x4 __attribute__((ext_vector_type(4)));
typedef __bf16 bf16x8 __attribute__((ext_vector_type(8)));
typedef float f32x4 __attribute__((ext_vector_type(4)));

typedef const __attribute__((address_space(1))) void* gas_t;
typedef __attribute__((address_space(3))) void* las_t;

__device__ inline f32x4 mfma_bf16(bf16x8 a, bf16x8 b, f32x4 c) {
    return __builtin_amdgcn_mfma_f32_16x16x32_bf16(a, b, c, 0, 0, 0);
}

// store 8 bf16 to LDS as two b64 (row strides are 8B- but not 16B-aligned)
__device__ inline void st8(bf16* p, bf16x8 v) {
    *(bf16x4*)p       = *(bf16x4*)&v;
    *(bf16x4*)(p + 4) = *((bf16x4*)&v + 1);
}
// load one MFMA operand fragment: elements 0..3 at k, 4..7 at k+16
__device__ inline bf16x8 ld_frag(const bf16* p) {
    bf16x8 r;
    *(bf16x4*)&r       = *(const bf16x4*)p;
    *((bf16x4*)&r + 1) = *(const bf16x4*)(p + 16);
    return r;
}
// FRAG-PERMUTED layout: global rows are pre-permuted per 64-elem K-block so
// slot s = kk*4+lg (16B) holds elements [kk*32+lg*4 .. +4, kk*32+lg*4+16 ..+20]
// = exactly one MFMA fragment -> single b128 read. LDS stores slot s of row r
// at chunk s ^ (r&7) (matches staging scol); banks: 2 lanes/bank = free.
__device__ inline bf16x8 ld_frag8(const bf16* tile, int row, int s) {
    return *(const bf16x8*)(tile + row * 64 + (((s) ^ (row & 7)) << 3));
}
// permute a float4-group index within its 64-elem (16-group) block: dst group
// G=(s<<1)|h  <-  src group (s>>2)*8 + h*4 + (s&3)
__device__ inline int perm_src4(int d4) {
    int G = d4 & 15;
    int s = G >> 1, h = G & 1;
    int srcG = ((s >> 2) << 3) + (h << 2) + (s & 3);
    return (d4 & ~15) | srcG;
}

// XCD-aware bijective block swizzle (nwg % 8 == 0): chunk grid per XCD so
// consecutive tiles (sharing an A panel) land on the same XCD's L2.
__device__ inline void swz_tile(int nx, int& m0, int& n0) {
    int flat = blockIdx.y * nx + blockIdx.x;
    int cpx = (nx * gridDim.y) >> 3;
    int s = (flat & 7) * cpx + (flat >> 3);
    n0 = (s % nx) * 128;
    m0 = (s / nx) * 128;
}

// ---------------- prep: sanitize x + cast both weights, one launch --------
// Writes xb/wqkv/wproj in FRAG-PERMUTED row layout (see ld_frag8).
// flat float4 space: [0,1048576) x | [1048576,1835008) qkv_w | rest proj_w
__global__ __launch_bounds__(256) void k_prep_all(const float* __restrict__ x,
                                                  const float* __restrict__ qw,
                                                  const float* __restrict__ pw,
                                                  bf16* __restrict__ xb,
                                                  bf16* __restrict__ wqkv,
                                                  bf16* __restrict__ wproj) {
    int idx = blockIdx.x * 1024 + threadIdx.x;
#pragma unroll
    for (int j = 0; j < 4; ++j, idx += 256) {
        if (idx < 1048576) {
            float4 v = ((const float4*)x)[perm_src4(idx)];
            float a[4] = {v.x, v.y, v.z, v.w};
            bf16x4 o;
#pragma unroll
            for (int q = 0; q < 4; ++q) {
                float f = a[q];
                f = __builtin_isfinite(f) ? fminf(fmaxf(f, -10000.f), 10000.f) : 0.f;
                o[q] = (bf16)f;
            }
            ((bf16x4*)xb)[idx] = o;
        } else if (idx < 1835008) {
            int i2 = idx - 1048576;
            float4 v = ((const float4*)qw)[perm_src4(i2)];
            bf16x4 o = {(bf16)v.x, (bf16)v.y, (bf16)v.z, (bf16)v.w};
            ((bf16x4*)wqkv)[i2] = o;
        } else {
            int i2 = idx - 1835008;
            float4 v = ((const float4*)pw)[perm_src4(i2)];
            bf16x4 o = {(bf16)v.x, (bf16)v.y, (bf16)v.z, (bf16)v.w};
            ((bf16x4*)wproj)[i2] = o;
        }
    }
}

// ---------------- generic GEMM (used for proj): C = A * Bt^T --------------
// m97 structure: 128x128 tile, BK=64, linear LDS + global_load_lds width=16,
// frag-permuted K layout -> single b128 frag reads. 4 waves, 64x64 each.
template <bool OUT_BF16, bool BIAS, bool SANITIZE>
__global__ __launch_bounds__(256) void k_gemm_bt(const bf16* __restrict__ A,
                                                 const bf16* __restrict__ Bt,
                                                 void* __restrict__ Cv,
                                                 const float* __restrict__ bias,
                                                 int N, int K) {
    __shared__ alignas(16) bf16 As[128 * 64];
    __shared__ alignas(16) bf16 Bs[128 * 64];
    const int t = threadIdx.x;
    int m0, n0;
    swz_tile(N >> 7, m0, n0);
    const int w = t >> 6, lane = t & 63;
    const int wm = (w >> 1) * 64, wn = (w & 1) * 64;
    const int lr = lane & 15, lg = lane >> 4;
    const int srow = lane >> 3;
    const int scol = ((lane & 7) ^ srow) * 8;   // pre-swizzled global chunk

    f32x4 acc[4][4];
#pragma unroll
    for (int i = 0; i < 4; ++i)
#pragma unroll
        for (int j = 0; j < 4; ++j) acc[i][j] = 0.0f;

    for (int k0 = 0; k0 < K; k0 += 64) {
#pragma unroll
        for (int i = 0; i < 4; ++i) {
            int rg = w * 32 + i * 8;
            __builtin_amdgcn_global_load_lds(
                (gas_t)(A + (size_t)(m0 + rg + srow) * K + k0 + scol),
                (las_t)(As + rg * 64), 16, 0, 0);
            __builtin_amdgcn_global_load_lds(
                (gas_t)(Bt + (size_t)(n0 + rg + srow) * K + k0 + scol),
                (las_t)(Bs + rg * 64), 16, 0, 0);
        }
        __syncthreads();
#pragma unroll
        for (int kk = 0; kk < 2; ++kk) {
            bf16x8 af[4], bfr[4];
#pragma unroll
            for (int mi = 0; mi < 4; ++mi)
                af[mi] = ld_frag8(As, wm + mi * 16 + lr, kk * 4 + lg);
#pragma unroll
            for (int ni = 0; ni < 4; ++ni)
                bfr[ni] = ld_frag8(Bs, wn + ni * 16 + lr, kk * 4 + lg);
#pragma unroll
            for (int mi = 0; mi < 4; ++mi)
#pragma unroll
                for (int ni = 0; ni < 4; ++ni)
                    acc[mi][ni] = mfma_bf16(af[mi], bfr[ni], acc[mi][ni]);
        }
        __syncthreads();
    }
#pragma unroll
    for (int mi = 0; mi < 4; ++mi) {
#pragma unroll
        for (int ni = 0; ni < 4; ++ni) {
            int col = n0 + wn + ni * 16 + lr;
            float bval = BIAS ? bias[col] : 0.f;
#pragma unroll
            for (int r = 0; r < 4; ++r) {
                int row = m0 + wm + mi * 16 + lg * 4 + r;
                float v = acc[mi][ni][r];
                if (SANITIZE) v = __builtin_isfinite(v) ? v : 0.f;
                v += bval;
                if (OUT_BF16)
                    ((bf16*)Cv)[(size_t)row * N + col] = (bf16)v;
                else
                    ((float*)Cv)[(size_t)row * N + col] = v;
            }
        }
    }
}

// ---------------- qkv GEMM with fused rmsnorm+rope+v-transpose ------------
// Single launch, single MFMA ordering (R14 structure); frag-permuted LDS
// reads (single b128, conflict-free). Epilogue: each wave's 64x64 tile =
// 64 seq rows x one full head of q, k, or v (normal C layout).
__global__ __launch_bounds__(256) void k_gemm_qkv(const bf16* __restrict__ A,
                                                  const bf16* __restrict__ Bt,
                                                  const float* __restrict__ pe,
                                                  const float* __restrict__ q_scale,
                                                  const float* __restrict__ k_scale,
                                                  bf16* __restrict__ qb,
                                                  bf16* __restrict__ kb,
                                                  bf16* __restrict__ vt) {
    __shared__ alignas(16) bf16 As[128 * 64];
    __shared__ alignas(16) bf16 Bs[128 * 64];
    const int K = DIMC, t = threadIdx.x;
    int m0, n0;
    swz_tile(24, m0, n0);
    const int w = t >> 6, lane = t & 63;
    const int wm = (w >> 1) * 64, wn = (w & 1) * 64;
    const int lr = lane & 15, lg = lane >> 4;
    const int srow = lane >> 3;
    const int scol = ((lane & 7) ^ srow) * 8;

    f32x4 acc[4][4];
#pragma unroll
    for (int i = 0; i < 4; ++i)
#pragma unroll
        for (int j = 0; j < 4; ++j) acc[i][j] = 0.0f;

    for (int k0 = 0; k0 < K; k0 += 64) {
#pragma unroll
        for (int i = 0; i < 4; ++i) {
            int rg = w * 32 + i * 8;
            __builtin_amdgcn_global_load_lds(
                (gas_t)(A + (size_t)(m0 + rg + srow) * K + k0 + scol),
                (las_t)(As + rg * 64), 16, 0, 0);
            __builtin_amdgcn_global_load_lds(
                (gas_t)(Bt + (size_t)(n0 + rg + srow) * K + k0 + scol),
                (las_t)(Bs + rg * 64), 16, 0, 0);
        }
        __syncthreads();
#pragma unroll
        for (int kk = 0; kk < 2; ++kk) {
            bf16x8 xf[4], wf[4];
#pragma unroll
            for (int i = 0; i < 4; ++i)
                xf[i] = ld_frag8(As, wm + i * 16 + lr, kk * 4 + lg);
#pragma unroll
            for (int i = 0; i < 4; ++i)
                wf[i] = ld_frag8(Bs, wn + i * 16 + lr, kk * 4 + lg);
#pragma unroll
            for (int mi = 0; mi < 4; ++mi)
#pragma unroll
                for (int ni = 0; ni < 4; ++ni)
                    acc[mi][ni] = mfma_bf16(xf[mi], wf[ni], acc[mi][ni]);
        }
        __syncthreads();
    }

    // ---- fused epilogue (normal layout: d = ni*16+lr, l = mi*16+lg*4+r) ----
    const int g = (n0 + wn) >> 6;          // head-slot 0..47
    const int sel = g >> 4;                // 0=q, 1=k, 2=v
    const int hh = g & 15;
    const int row0 = m0 + wm;              // global row base of wave tile
    const int bb = row0 >> 11;
    const int l0 = row0 & (SEQ - 1);
    const size_t bhh = (size_t)(bb * HEADS + hh);

    // nan_to_num (reference sanitizes qkv before norm/rope)
#pragma unroll
    for (int mi = 0; mi < 4; ++mi)
#pragma unroll
        for (int ni = 0; ni < 4; ++ni)
#pragma unroll
            for (int r = 0; r < 4; ++r) {
                float v = acc[mi][ni][r];
                acc[mi][ni][r] = __builtin_isfinite(v) ? v : 0.f;
            }

    if (sel == 2) {
        // V: write transposed [B,H,D,L]; 4 consecutive L per lane
#pragma unroll
        for (int mi = 0; mi < 4; ++mi)
#pragma unroll
            for (int ni = 0; ni < 4; ++ni) {
                bf16x4 ov;
#pragma unroll
                for (int r = 0; r < 4; ++r) ov[r] = (bf16)acc[mi][ni][r];
                *(bf16x4*)(vt + (bhh * HD + ni * 16 + lr) * SEQ +
                           l0 + mi * 16 + lg * 4) = ov;
            }
    } else {
        const float* sc = sel ? k_scale : q_scale;
        bf16* dst = sel ? kb : qb;
        // fold D^-0.5 * log2(e) into q
        const float oscale = sel ? 1.0f : 0.125f * 1.44269504088896340736f;
        float scv[4];
#pragma unroll
        for (int ni = 0; ni < 4; ++ni) scv[ni] = sc[ni * 16 + lr];
#pragma unroll
        for (int mi = 0; mi < 4; ++mi) {
#pragma unroll
            for (int r = 0; r < 4; ++r) {
                float ss = 0.f;
#pragma unroll
                for (int ni = 0; ni < 4; ++ni)
                    ss += acc[mi][ni][r] * acc[mi][ni][r];
                ss += __shfl_xor(ss, 1, 64);
                ss += __shfl_xor(ss, 2, 64);
                ss += __shfl_xor(ss, 4, 64);
                ss += __shfl_xor(ss, 8, 64);
                float rms = rsqrtf(ss * (1.f / 64.f) + 1e-6f);
                int l = l0 + mi * 16 + lg * 4 + r;
                const float* peb = pe + (size_t)l * 128 + (lr & 1) * 2;
                bf16* db = dst + (bhh * SEQ + l) * HD + lr;
#pragma unroll
                for (int ni = 0; ni < 4; ++ni) {
                    float e = acc[mi][ni][r] * rms * scv[ni];
                    float p = __shfl_xor(e, 1, 64);
                    float2 pv = *(const float2*)(peb + (ni * 8 + (lr >> 1)) * 4);
                    float ee = (lr & 1) ? p : e;
                    float eo = (lr & 1) ? e : p;
                    db[ni * 16] = (bf16)((pv.x * ee + pv.y * eo) * oscale);
                }
            }
        }
    }
}

// ---------------- flash attention (swapped QK^T, register P, O^T PV) ------
// 1D grid of 512 blocks, XCD-swizzled so each XCD owns 4 heads (K/V
// L2-resident, FETCH ~12MB measured). 512 threads = 8 waves, wave w ->
// q rows w*16..+16 of a 128-row tile. KVBLK=128 (16 barriers, 36 MFMA/tile).
// NO-SHIFT softmax (P = exp2(s) directly); l via ones-MFMA.
// Reg-staged double-buffered K/V; V as two [64][68] half-buffers (0-conflict).
// O written in the FRAG-PERMUTED column layout that k_gemm_bt expects.
__global__ __launch_bounds__(512) void k_attn(const bf16* __restrict__ Q,
                                              const bf16* __restrict__ Kb,
                                              const bf16* __restrict__ Vt,
                                              bf16* __restrict__ O) {
    __shared__ bf16 Ks[2][128][68];     // keys x d        34,816 B
    __shared__ bf16 Vs[2][2][64][68];   // half, d x keys  34,816 B
    const int bid = blockIdx.x;
    const int s_id = (bid & 7) * 64 + (bid >> 3);
    const int qt = s_id & 15, bh = s_id >> 4;
    const int b = bh >> 4, h = bh & 15;
    const int t = threadIdx.x, w = t >> 6, lane = t & 63;
    const int lr = lane & 15, lg = lane >> 4;
    const size_t baseQK = (size_t)bh * SEQ * HD;
    const size_t baseVt = (size_t)bh * HD * SEQ;

    // Q fragments straight from global (lane-private; 4 x 8B loads)
    const bf16* qp = Q + baseQK + (size_t)(qt * 128 + w * 16 + lr) * HD;
    bf16x8 qf0 = ld_frag(qp + lg * 4);
    bf16x8 qf1 = ld_frag(qp + 32 + lg * 4);

    // staging: K rows t>>3 and 64+(t>>3), col (t&7)*8; V halves row t>>3.
    const int sr = t >> 3, sc8 = (t & 7) * 8;
    const bf16* kg0 = Kb + baseQK + (size_t)sr * HD + sc8;
    const bf16* vg0 = Vt + baseVt + (size_t)sr * SEQ + sc8;
    // stage K/V tile 0
    {
        bf16x8 k0 = *(const bf16x8*)(kg0);
        bf16x8 k1 = *(const bf16x8*)(kg0 + (size_t)64 * HD);
        bf16x8 v0 = *(const bf16x8*)(vg0);
        bf16x8 v1 = *(const bf16x8*)(vg0 + 64);
        st8(&Ks[0][sr][sc8], k0);
        st8(&Ks[0][64 + sr][sc8], k1);
        st8(&Vs[0][0][sr][sc8], v0);
        st8(&Vs[0][1][sr][sc8], v1);
    }
    __syncthreads();

    bf16x8 ones;
#pragma unroll
    for (int j = 0; j < 8; ++j) ones[j] = (bf16)1.0f;

    f32x4 oacc[4];
#pragma unroll
    for (int i = 0; i < 4; ++i) oacc[i] = 0.0f;
    f32x4 lacc = 0.0f;

    int cur = 0;
    for (int kt = 0; kt < SEQ / 128; ++kt) {
        // issue next tile's global loads early (latency hidden under compute)
        bf16x8 k0r, k1r, v0r, v1r;
        const bool pf = (kt + 1) < SEQ / 128;
        if (pf) {
            const bf16* kg = kg0 + (size_t)(kt + 1) * 128 * HD;
            const bf16* vg = vg0 + (kt + 1) * 128;
            k0r = *(const bf16x8*)(kg);
            k1r = *(const bf16x8*)(kg + (size_t)64 * HD);
            v0r = *(const bf16x8*)(vg);
            v1r = *(const bf16x8*)(vg + 64);
        }
        // QK^T on current tile: 8 key-blocks x 2 d-halves
        __builtin_amdgcn_s_setprio(1);
        f32x4 s[8];
#pragma unroll
        for (int nk = 0; nk < 8; ++nk) {
            f32x4 a = 0.0f;
            a = mfma_bf16(ld_frag(&Ks[cur][nk * 16 + lr][lg * 4]), qf0, a);
            a = mfma_bf16(ld_frag(&Ks[cur][nk * 16 + lr][32 + lg * 4]), qf1, a);
            s[nk] = a;
        }
        __builtin_amdgcn_s_setprio(0);
        // P = exp2(s), packed straight into A-frag layout
        bf16x8 pa[4];
#pragma unroll
        for (int c = 0; c < 4; ++c)
#pragma unroll
            for (int j = 0; j < 4; ++j) {
                pa[c][j]     = (bf16)exp2f(s[2 * c][j]);
                pa[c][4 + j] = (bf16)exp2f(s[2 * c + 1][j]);
            }
        __builtin_amdgcn_s_setprio(1);
        // l row-sum via ones-MFMA (lands in col q = lane&15, all regs equal)
#pragma unroll
        for (int c = 0; c < 4; ++c) lacc = mfma_bf16(ones, pa[c], lacc);
        // PV over 4 key-chunks of 32: half = c>>1, local col = (c&1)*32
#pragma unroll
        for (int nd = 0; nd < 4; ++nd)
#pragma unroll
            for (int c = 0; c < 4; ++c)
                oacc[nd] = mfma_bf16(
                    ld_frag(&Vs[cur][c >> 1][nd * 16 + lr][(c & 1) * 32 + lg * 4]),
                    pa[c], oacc[nd]);
        __builtin_amdgcn_s_setprio(0);
        if (pf) {
            st8(&Ks[cur ^ 1][sr][sc8], k0r);
            st8(&Ks[cur ^ 1][64 + sr][sc8], k1r);
            st8(&Vs[cur ^ 1][0][sr][sc8], v0r);
            st8(&Vs[cur ^ 1][1][sr][sc8], v1r);
        }
        __syncthreads();
        cur ^= 1;
    }
    // epilogue: O^T[d][q] regs -> O[b, q, head-block col in frag-permuted
    // layout]: element d = nd*16+lg*4+r maps to slot (nd>>1)*4+lg, half nd&1.
    {
        float inv = 1.f / lacc[0];
        int q = qt * 128 + w * 16 + lr;
#pragma unroll
        for (int nd = 0; nd < 4; ++nd) {
            bf16x4 ov;
#pragma unroll
            for (int r2 = 0; r2 < 4; ++r2) {
                float v = oacc[nd][r2] * inv;
                v = fminf(fmaxf(v, -10000.f), 10000.f);
                ov[r2] = (bf16)v;
            }
            int colb = (((nd >> 1) * 4 + lg) << 3) + (nd & 1) * 4;
            *(bf16x4*)(O + ((size_t)(b * SEQ + q)) * DIMC + h * HD + colb) = ov;
        }
    }
}

extern "C" void kernel_launch(void* const* d_in, const int* in_sizes, int n_in,
                              void* d_out, int out_size, void* d_ws, size_t ws_size,
                              hipStream_t stream) {
    const float* x = (const float*)d_in[0];
    const float* pe = (const float*)d_in[1];
    const float* qkv_w = (const float*)d_in[2];
    const float* q_scale = (const float*)d_in[3];
    const float* k_scale = (const float*)d_in[4];
    const float* proj_w = (const float*)d_in[5];
    const float* proj_b = (const float*)d_in[6];
    float* out = (float*)d_out;
    char* ws = (char*)d_ws;

    // workspace layout (48 MB used)
    bf16* xb = (bf16*)(ws);                              // 8 MB  [4096][1024] (frag-permuted K)
    bf16* wqkv = (bf16*)(ws + (8u << 20));               // 6 MB  [3072][1024] (frag-permuted K)
    bf16* wproj = (bf16*)(ws + (14u << 20));             // 2 MB  [1024][1024] (frag-permuted K)
    bf16* ao = (bf16*)(ws + (16u << 20));                // 8 MB  attn out (frag-permuted cols)
    bf16* qb = (bf16*)(ws + (24u << 20));                // 8 MB  [B,H,L,D]
    bf16* kb = (bf16*)(ws + (32u << 20));                // 8 MB  [B,H,L,D]
    bf16* vt = (bf16*)(ws + (40u << 20));                // 8 MB  [B,H,D,L]

    k_prep_all<<<2048, 256, 0, stream>>>(x, qkv_w, proj_w, xb, wqkv, wproj);
    // qkv GEMM + fused nan_to_num/rmsnorm/rope/v-transpose (single launch)
    k_gemm_qkv<<<dim3(24, 32), 256, 0, stream>>>(xb, wqkv, pe, q_scale, k_scale,
                                                 qb, kb, vt);
    k_attn<<<512, 512, 0, stream>>>(qb, kb, vt, ao);
    // out = attn_out @ proj_w^T + proj_b (clip already applied in k_attn)
    k_gemm_bt<false, true, false>
        <<<dim3(8, 32), 256, 0, stream>>>(ao, wproj, (void*)out, proj_b, 1024, 1024);
}